// Round 1
// baseline (101.457 us; speedup 1.0000x reference)
//
#include <hip/hip_runtime.h>
#include <math.h>

// Problem constants (from reference)
#define BATCH    32
#define LSEQ     512
#define DDIM     1024
#define NSEC     4
#define SSIZE    256          // K dimension
#define LATENT   256          // output cols
#define NTOK     32
#define COEF     0.1f

#define ROWS     (BATCH * NTOK * NSEC)   // 4096
#define COLS     LATENT                  // 256
#define KDIM     SSIZE                   // 256

#define TILE     64
#define BK       64
#define LDS_STRIDE 68   // 64 + 4 pad; 68*4B = 272B = 17*16B -> b128-aligned rows, 2-way-max bank aliasing

// Semantics collapse: M = inverse(C) exactly, and mask is constant along the
// transformed (batch) axis, so IDCT(mask*DCT(x)) == mask*x. Kernel computes
//   out[row, o] = tanh( scale(row) * dot(enc_row, W[o,:]) + bias[o] )
// where row = ((b*32 + l)*4 + n), enc_row = enc[b, l, n, :],
// scale = 1.0 for (n==0) or (n==1 && l>=16), else 0.1  (for l < 32).

__global__ __launch_bounds__(256, 4)
void spectral_gemm_kernel(const float* __restrict__ enc,
                          const float* __restrict__ W,
                          const float* __restrict__ bias,
                          float* __restrict__ out) {
    // K-major (transposed) tiles: tile[k][r], stride LDS_STRIDE
    __shared__ float As[BK * LDS_STRIDE];
    __shared__ float Ws[BK * LDS_STRIDE];

    const int t      = threadIdx.x;
    const int tile_r = blockIdx.x * TILE;   // 64 row-tiles
    const int tile_c = blockIdx.y * TILE;   // 4 col-tiles

    // compute mapping: 16x16 thread grid, 4x4 micro-tile
    const int tx = t & 15;    // col group
    const int ty = t >> 4;    // row group

    // staging mapping: r = t>>2 in [0,64), k4 base = t&3 (consecutive threads ->
    // consecutive float4 in K => coalesced)
    const int sr  = t >> 2;
    const int k4b = t & 3;

    const int row_g = tile_r + sr;
    const int n = row_g & 3;
    const int l = (row_g >> 2) & 31;
    const float scale = (n == 0 || (n == 1 && l >= 16)) ? 1.0f : COEF;
    // enc[b, l, n, s] flat = b*L*D + l*D + n*256 + s = (row>>7)*524288 + (row&127)*256 + s
    const long a_base = (long)(row_g >> 7) * (long)(LSEQ * DDIM)
                      + (long)(row_g & 127) * 256;
    const int  o_g    = tile_c + sr;        // W row for staging

    float acc[4][4] = {{0.f,0.f,0.f,0.f},{0.f,0.f,0.f,0.f},
                       {0.f,0.f,0.f,0.f},{0.f,0.f,0.f,0.f}};

    for (int kk = 0; kk < KDIM; kk += BK) {
        // ---- stage A (with row scale) and W, transposed into [k][r] ----
        #pragma unroll
        for (int it = 0; it < 4; ++it) {
            const int k4 = k4b + it * 4;          // float4 column in [0,16)
            const int kl = k4 * 4;                // k_local

            float4 va = *(const float4*)&enc[a_base + kk + k4 * 4];
            va.x *= scale; va.y *= scale; va.z *= scale; va.w *= scale;
            As[(kl + 0) * LDS_STRIDE + sr] = va.x;
            As[(kl + 1) * LDS_STRIDE + sr] = va.y;
            As[(kl + 2) * LDS_STRIDE + sr] = va.z;
            As[(kl + 3) * LDS_STRIDE + sr] = va.w;

            float4 vw = *(const float4*)&W[o_g * KDIM + kk + k4 * 4];
            Ws[(kl + 0) * LDS_STRIDE + sr] = vw.x;
            Ws[(kl + 1) * LDS_STRIDE + sr] = vw.y;
            Ws[(kl + 2) * LDS_STRIDE + sr] = vw.z;
            Ws[(kl + 3) * LDS_STRIDE + sr] = vw.w;
        }
        __syncthreads();

        // ---- inner product: b128 fragment reads, 16 FMA per k ----
        #pragma unroll 8
        for (int k = 0; k < BK; ++k) {
            const float4 a = *(const float4*)&As[k * LDS_STRIDE + ty * 4];
            const float4 w = *(const float4*)&Ws[k * LDS_STRIDE + tx * 4];
            acc[0][0] += a.x * w.x; acc[0][1] += a.x * w.y;
            acc[0][2] += a.x * w.z; acc[0][3] += a.x * w.w;
            acc[1][0] += a.y * w.x; acc[1][1] += a.y * w.y;
            acc[1][2] += a.y * w.z; acc[1][3] += a.y * w.w;
            acc[2][0] += a.z * w.x; acc[2][1] += a.z * w.y;
            acc[2][2] += a.z * w.z; acc[2][3] += a.z * w.w;
            acc[3][0] += a.w * w.x; acc[3][1] += a.w * w.y;
            acc[3][2] += a.w * w.z; acc[3][3] += a.w * w.w;
        }
        __syncthreads();
    }

    // ---- epilogue: bias + tanh, vectorized store ----
    const float4 bv = *(const float4*)&bias[tile_c + tx * 4];
    #pragma unroll
    for (int i = 0; i < 4; ++i) {
        const int row = tile_r + ty * 4 + i;
        float4 o;
        o.x = tanhf(acc[i][0] + bv.x);
        o.y = tanhf(acc[i][1] + bv.y);
        o.z = tanhf(acc[i][2] + bv.z);
        o.w = tanhf(acc[i][3] + bv.w);
        *(float4*)&out[(long)row * COLS + tile_c + tx * 4] = o;
    }
}

extern "C" void kernel_launch(void* const* d_in, const int* in_sizes, int n_in,
                              void* d_out, int out_size, void* d_ws, size_t ws_size,
                              hipStream_t stream) {
    const float* enc  = (const float*)d_in[0];   // [32, 512, 1024]
    const float* W    = (const float*)d_in[1];   // [256, 256]
    const float* bias = (const float*)d_in[2];   // [256]
    float* out = (float*)d_out;                  // [32, 32, 4, 256]

    dim3 grid(ROWS / TILE, COLS / TILE);         // 64 x 4 = 256 blocks
    dim3 block(256);
    spectral_gemm_kernel<<<grid, block, 0, stream>>>(enc, W, bias, out);
}